// Round 7
// baseline (80.410 us; speedup 1.0000x reference)
//
#include <hip/hip_runtime.h>

#define HH 1024
#define WW 1024
#define NR 16                          // output rows per block
#define STRIPS (HH / NR)               // 64 strips per image
#define NBLK (32 * STRIPS)             // 2048 blocks, 8192 waves

struct Row { float l; float4 v; float r; };

__device__ __forceinline__ Row ldrow(const float* __restrict__ img, int y,
                                     int x0, int xl, int xr) {
    const float* p = img + (size_t)y * WW;
    Row r;
    r.v = *reinterpret_cast<const float4*>(p + x0);
    r.l = p[xl];                        // clamped halo: neighbor's cache line (L1 hit)
    r.r = p[xr];
    return r;
}

__global__ __launch_bounds__(256) void sobel_loss_kernel(
    const float* __restrict__ fake, const float* __restrict__ real,
    float* __restrict__ pnum, unsigned int* __restrict__ pcnt)
{
    const int t  = threadIdx.x;
    const int b  = blockIdx.x / STRIPS;
    const int y0 = (blockIdx.x % STRIPS) * NR;
    const float* fimg = fake + (size_t)b * HH * WW;
    const float* rimg = real + (size_t)b * HH * WW;

    const int x0 = 4 * t;
    const int xl = max(x0 - 1, 0);          // clamp -> edge replicate
    const int xr = min(x0 + 4, WW - 1);

    float num = 0.f;
    int   cnt = 0;

    auto proc = [&](const Row& fa, const Row& fb, const Row& fc,
                    const Row& ra, const Row& rb, const Row& rc) {
        // vertical smooth S = (p + 2c) + n  — exact jax FP order
        const float fSm = fa.l + 2.f * fb.l + fc.l;
        const float rSm = ra.l + 2.f * rb.l + rc.l;
        float4 fS, rS;
        fS.x = fa.v.x + 2.f * fb.v.x + fc.v.x;
        fS.y = fa.v.y + 2.f * fb.v.y + fc.v.y;
        fS.z = fa.v.z + 2.f * fb.v.z + fc.v.z;
        fS.w = fa.v.w + 2.f * fb.v.w + fc.v.w;
        rS.x = ra.v.x + 2.f * rb.v.x + rc.v.x;
        rS.y = ra.v.y + 2.f * rb.v.y + rc.v.y;
        rS.z = ra.v.z + 2.f * rb.v.z + rc.v.z;
        rS.w = ra.v.w + 2.f * rb.v.w + rc.v.w;
        const float fSp = fa.r + 2.f * fb.r + fc.r;
        const float rSp = ra.r + 2.f * rb.r + rc.r;

        float ef, er;
        er = rS.y - rSm;  ef = fS.y - fSm;  if (er > 0.f) { num += fabsf(ef - er); ++cnt; }
        er = rS.z - rS.x; ef = fS.z - fS.x; if (er > 0.f) { num += fabsf(ef - er); ++cnt; }
        er = rS.w - rS.y; ef = fS.w - fS.y; if (er > 0.f) { num += fabsf(ef - er); ++cnt; }
        er = rSp - rS.z;  ef = fSp - fS.z;  if (er > 0.f) { num += fabsf(ef - er); ++cnt; }
    };

    // rolling window: rows (y-1, y) entering each 2-row group
    Row fp_ = ldrow(fimg, max(y0 - 1, 0), x0, xl, xr);
    Row fc_ = ldrow(fimg, y0,             x0, xl, xr);
    Row rp_ = ldrow(rimg, max(y0 - 1, 0), x0, xl, xr);
    Row rc_ = ldrow(rimg, y0,             x0, xl, xr);

    #pragma unroll
    for (int g = 0; g < NR / 2; ++g) {
        const int y = y0 + 2 * g;
        // issue ALL loads for this 2-row group before any compute:
        // one latency exposure per 2 output rows
        Row fn1 = ldrow(fimg, y + 1,               x0, xl, xr);
        Row fn2 = ldrow(fimg, min(y + 2, HH - 1),  x0, xl, xr);
        Row rn1 = ldrow(rimg, y + 1,               x0, xl, xr);
        Row rn2 = ldrow(rimg, min(y + 2, HH - 1),  x0, xl, xr);

        proc(fp_, fc_, fn1, rp_, rc_, rn1);   // output row y
        proc(fc_, fn1, fn2, rc_, rn1, rn2);   // output row y+1

        fp_ = fn1; fc_ = fn2;
        rp_ = rn1; rc_ = rn2;
    }

    // wave reduce -> block reduce -> ONE plain store per block (no atomics)
    for (int off = 32; off; off >>= 1) {
        num += __shfl_down(num, off);
        cnt += __shfl_down(cnt, off);
    }
    __shared__ float wnum[4];
    __shared__ int   wcnt[4];
    const int wave = t >> 6, lane = t & 63;
    if (lane == 0) { wnum[wave] = num; wcnt[wave] = cnt; }
    __syncthreads();
    if (t == 0) {
        pnum[blockIdx.x] = wnum[0] + wnum[1] + wnum[2] + wnum[3];
        pcnt[blockIdx.x] = (unsigned int)(wcnt[0] + wcnt[1] + wcnt[2] + wcnt[3]);
    }
}

__global__ __launch_bounds__(256) void reduce_kernel(
    const float* __restrict__ pnum, const unsigned int* __restrict__ pcnt,
    float* __restrict__ out)
{
    const int t = threadIdx.x;
    double             n = 0.0;
    unsigned long long c = 0;
    for (int i = t; i < NBLK; i += 256) { n += (double)pnum[i]; c += pcnt[i]; }
    for (int off = 32; off; off >>= 1) {
        n += __shfl_down(n, off);
        c += __shfl_down(c, off);
    }
    __shared__ double             sn[4];
    __shared__ unsigned long long sc[4];
    const int wave = t >> 6, lane = t & 63;
    if (lane == 0) { sn[wave] = n; sc[wave] = c; }
    __syncthreads();
    if (t == 0) {
        const double N = sn[0] + sn[1] + sn[2] + sn[3];
        const double C = (double)(sc[0] + sc[1] + sc[2] + sc[3]);
        out[0] = (float)(N / C / 32.0);
    }
}

extern "C" void kernel_launch(void* const* d_in, const int* in_sizes, int n_in,
                              void* d_out, int out_size, void* d_ws, size_t ws_size,
                              hipStream_t stream)
{
    const float* fake = (const float*)d_in[0];
    const float* real = (const float*)d_in[1];
    float* out = (float*)d_out;

    float*        pnum = (float*)d_ws;                            // 2048 floats
    unsigned int* pcnt = (unsigned int*)((char*)d_ws + NBLK * 4); // 2048 uints

    sobel_loss_kernel<<<NBLK, 256, 0, stream>>>(fake, real, pnum, pcnt);
    reduce_kernel<<<1, 256, 0, stream>>>(pnum, pcnt, out);
}

// Round 8
// 52.725 us; speedup vs baseline: 1.5251x; 1.5251x over previous
//
#include <hip/hip_runtime.h>

#define HH 1024
#define WW 1024
#define NR 16                          // output rows per block
#define STRIPS (HH / NR)               // 64 strips per image
#define NBLK (32 * STRIPS)             // 2048 blocks, 8192 waves

// wave-quarter-row: float4 payload + 2 wave-uniform seam scalars
struct RowQ { float4 v; float sl; float sr; };

__device__ __forceinline__ RowQ ldq(const float* __restrict__ img, int y,
                                    int x0, int xsl, int xsr) {
    const float* p = img + (size_t)y * WW;
    RowQ r;
    r.v  = *reinterpret_cast<const float4*>(p + x0);
    r.sl = p[xsl];                      // wave-uniform -> 1-line broadcast
    r.sr = p[xsr];
    return r;
}

__global__ __launch_bounds__(256) void sobel_loss_kernel(
    const float* __restrict__ fake, const float* __restrict__ real,
    float* __restrict__ pnum, unsigned int* __restrict__ pcnt)
{
    const int t    = threadIdx.x;
    const int lane = t & 63;
    const int wv   = t >> 6;                       // quarter-row 0..3
    const int b    = blockIdx.x / STRIPS;
    const int y0   = (blockIdx.x % STRIPS) * NR;
    const float* fimg = fake + (size_t)b * HH * WW;
    const float* rimg = real + (size_t)b * HH * WW;

    const int x0  = 256 * wv + 4 * lane;           // this thread's 4 px
    const int xsl = max(256 * wv - 1, 0);          // left seam col (clamped)
    const int xsr = min(256 * wv + 256, WW - 1);   // right seam col (clamped)

    float num = 0.f;
    int   cnt = 0;

    auto proc = [&](const RowQ& fa, const RowQ& fb, const RowQ& fc,
                    const RowQ& ra, const RowQ& rb, const RowQ& rc) {
        // vertical smooth S = (p + 2c) + n  — exact jax FP order
        float4 fS, rS;
        fS.x = fa.v.x + 2.f * fb.v.x + fc.v.x;
        fS.y = fa.v.y + 2.f * fb.v.y + fc.v.y;
        fS.z = fa.v.z + 2.f * fb.v.z + fc.v.z;
        fS.w = fa.v.w + 2.f * fb.v.w + fc.v.w;
        rS.x = ra.v.x + 2.f * rb.v.x + rc.v.x;
        rS.y = ra.v.y + 2.f * rb.v.y + rc.v.y;
        rS.z = ra.v.z + 2.f * rb.v.z + rc.v.z;
        rS.w = ra.v.w + 2.f * rb.v.w + rc.v.w;
        // seam smooth (same FP order -> bit-identical to neighbor's S)
        const float fSL = fa.sl + 2.f * fb.sl + fc.sl;
        const float fSR = fa.sr + 2.f * fb.sr + fc.sr;
        const float rSL = ra.sl + 2.f * rb.sl + rc.sl;
        const float rSR = ra.sr + 2.f * rb.sr + rc.sr;

        // horizontal neighbors via intra-wave shuffle of computed S
        const float fup = __shfl_up(fS.w, 1);
        const float rup = __shfl_up(rS.w, 1);
        const float fdn = __shfl_down(fS.x, 1);
        const float rdn = __shfl_down(rS.x, 1);
        const float fSm = (lane == 0)  ? fSL : fup;
        const float rSm = (lane == 0)  ? rSL : rup;
        const float fSp = (lane == 63) ? fSR : fdn;
        const float rSp = (lane == 63) ? rSR : rdn;

        float ef, er;
        er = rS.y - rSm;  ef = fS.y - fSm;  if (er > 0.f) { num += fabsf(ef - er); ++cnt; }
        er = rS.z - rS.x; ef = fS.z - fS.x; if (er > 0.f) { num += fabsf(ef - er); ++cnt; }
        er = rS.w - rS.y; ef = fS.w - fS.y; if (er > 0.f) { num += fabsf(ef - er); ++cnt; }
        er = rSp - rS.z;  ef = fSp - fS.z;  if (er > 0.f) { num += fabsf(ef - er); ++cnt; }
    };

    // rolling 3-row window, load->consume immediately (keeps VGPR low, cf. R5)
    RowQ fp_ = ldq(fimg, max(y0 - 1, 0), x0, xsl, xsr);
    RowQ fc_ = ldq(fimg, y0,             x0, xsl, xsr);
    RowQ rp_ = ldq(rimg, max(y0 - 1, 0), x0, xsl, xsr);
    RowQ rc_ = ldq(rimg, y0,             x0, xsl, xsr);

    #pragma unroll
    for (int i = 0; i < NR; ++i) {
        const int yn = min(y0 + i + 1, HH - 1);
        RowQ fn_ = ldq(fimg, yn, x0, xsl, xsr);
        RowQ rn_ = ldq(rimg, yn, x0, xsl, xsr);

        proc(fp_, fc_, fn_, rp_, rc_, rn_);

        fp_ = fc_; fc_ = fn_;
        rp_ = rc_; rc_ = rn_;
    }

    // wave reduce -> block reduce -> ONE plain store per block (no atomics)
    for (int off = 32; off; off >>= 1) {
        num += __shfl_down(num, off);
        cnt += __shfl_down(cnt, off);
    }
    __shared__ float wnum[4];
    __shared__ int   wcnt[4];
    if (lane == 0) { wnum[wv] = num; wcnt[wv] = cnt; }
    __syncthreads();
    if (t == 0) {
        pnum[blockIdx.x] = wnum[0] + wnum[1] + wnum[2] + wnum[3];
        pcnt[blockIdx.x] = (unsigned int)(wcnt[0] + wcnt[1] + wcnt[2] + wcnt[3]);
    }
}

__global__ __launch_bounds__(256) void reduce_kernel(
    const float* __restrict__ pnum, const unsigned int* __restrict__ pcnt,
    float* __restrict__ out)
{
    const int t = threadIdx.x;
    double             n = 0.0;
    unsigned long long c = 0;
    for (int i = t; i < NBLK; i += 256) { n += (double)pnum[i]; c += pcnt[i]; }
    for (int off = 32; off; off >>= 1) {
        n += __shfl_down(n, off);
        c += __shfl_down(c, off);
    }
    __shared__ double             sn[4];
    __shared__ unsigned long long sc[4];
    const int wave = t >> 6, lane = t & 63;
    if (lane == 0) { sn[wave] = n; sc[wave] = c; }
    __syncthreads();
    if (t == 0) {
        const double N = sn[0] + sn[1] + sn[2] + sn[3];
        const double C = (double)(sc[0] + sc[1] + sc[2] + sc[3]);
        out[0] = (float)(N / C / 32.0);
    }
}

extern "C" void kernel_launch(void* const* d_in, const int* in_sizes, int n_in,
                              void* d_out, int out_size, void* d_ws, size_t ws_size,
                              hipStream_t stream)
{
    const float* fake = (const float*)d_in[0];
    const float* real = (const float*)d_in[1];
    float* out = (float*)d_out;

    float*        pnum = (float*)d_ws;                            // 2048 floats
    unsigned int* pcnt = (unsigned int*)((char*)d_ws + NBLK * 4); // 2048 uints

    sobel_loss_kernel<<<NBLK, 256, 0, stream>>>(fake, real, pnum, pcnt);
    reduce_kernel<<<1, 256, 0, stream>>>(pnum, pcnt, out);
}